// Round 1
// 245.818 us; speedup vs baseline: 1.0559x; 1.0559x over previous
//
#include <hip/hip_runtime.h>

typedef __attribute__((ext_vector_type(4))) int int4v;

#define NB_MAX 1024  // partial-max array length

// --- async global->LDS, 16B per lane, wave-uniform LDS base ---
__device__ __forceinline__ void async_ld16(const void* g, void* l) {
  __builtin_amdgcn_global_load_lds(
      (const __attribute__((address_space(1))) void*)g,
      (__attribute__((address_space(3))) void*)l,
      16, 0, 0);
}

// ---------------- 1) absmax partials over x (no atomics, no memset) --------
__global__ void absmax_partial_kernel(const float* __restrict__ x,
                                      float* __restrict__ partial, int n4) {
  const float4* x4 = (const float4*)x;
  float m = 0.0f;
  for (int i = blockIdx.x * blockDim.x + threadIdx.x; i < n4;
       i += gridDim.x * blockDim.x) {
    float4 v = x4[i];
    m = fmaxf(m, fabsf(v.x));
    m = fmaxf(m, fabsf(v.y));
    m = fmaxf(m, fabsf(v.z));
    m = fmaxf(m, fabsf(v.w));
  }
#pragma unroll
  for (int off = 32; off > 0; off >>= 1)
    m = fmaxf(m, __shfl_down(m, off, 64));
  __shared__ float wmax[4];
  const int wid = threadIdx.x >> 6;
  if ((threadIdx.x & 63) == 0) wmax[wid] = m;
  __syncthreads();
  if (threadIdx.x == 0)
    partial[blockIdx.x] =
        fmaxf(fmaxf(wmax[0], wmax[1]), fmaxf(wmax[2], wmax[3]));
}

// block-wide reduce of the 1024 partials (every block recomputes; ~L2 hits)
__device__ __forceinline__ float reduce_partials(const float* partial) {
  __shared__ float smax;
  float m = 0.0f;
  for (int i = threadIdx.x; i < NB_MAX; i += blockDim.x)
    m = fmaxf(m, partial[i]);
#pragma unroll
  for (int off = 32; off > 0; off >>= 1)
    m = fmaxf(m, __shfl_down(m, off, 64));
  __shared__ float wmax[4];
  const int wid = threadIdx.x >> 6;
  if ((threadIdx.x & 63) == 0) wmax[wid] = m;
  __syncthreads();
  if (threadIdx.x == 0)
    smax = fmaxf(fmaxf(wmax[0], wmax[1]), fmaxf(wmax[2], wmax[3]));
  __syncthreads();
  return smax;
}

// ---------------- 2) fused: quantize x -> int8  AND  pack w -> int8 -------
__global__ void quant_pack_kernel(const float* __restrict__ x,
                                  const int* __restrict__ w,
                                  const float* __restrict__ partial,
                                  float* __restrict__ scale_slot,
                                  int* __restrict__ qx, int* __restrict__ qw,
                                  int nx4, int nw4) {
  const float scale = reduce_partials(partial) / 127.0f;
  const int i = blockIdx.x * blockDim.x + threadIdx.x;
  if (i == 0) *scale_slot = scale;  // benign same-value race if multiple wrote
  if (i < nx4) {
    float4 v = ((const float4*)x)[i];
    // IEEE division + rint (half-to-even) matches jnp.round(t/scale)
    int q0 = (int)fminf(fmaxf(rintf(v.x / scale), -127.0f), 127.0f);
    int q1 = (int)fminf(fmaxf(rintf(v.y / scale), -127.0f), 127.0f);
    int q2 = (int)fminf(fmaxf(rintf(v.z / scale), -127.0f), 127.0f);
    int q3 = (int)fminf(fmaxf(rintf(v.w / scale), -127.0f), 127.0f);
    unsigned int p = (unsigned int)(q0 & 255) |
                     ((unsigned int)(q1 & 255) << 8) |
                     ((unsigned int)(q2 & 255) << 16) |
                     ((unsigned int)(q3 & 255) << 24);
    qx[i] = (int)p;
  }
  if (i < nw4) {
    int4 v = ((const int4*)w)[i];
    unsigned int p = (unsigned int)(v.x & 255) |
                     ((unsigned int)(v.y & 255) << 8) |
                     ((unsigned int)(v.z & 255) << 16) |
                     ((unsigned int)(v.w & 255) << 24);
    qw[i] = (int)p;
  }
}

// ---------------- 3) int8 GEMM: 256x256 tile, 8-wave, 4-phase pipeline ----
// T2+T3+T4+T5 port of the verified 256-sq 8-phase template to i8:
//  - BK = 128 bytes -> byte-isomorphic to the bf16 m201 geometry (128B rows)
//  - 8 waves (2M x 4N), per-wave 128x64 output = acc[8][4] of 16x16
//  - K-tile = 4 phases of 16 MFMA (one C-quadrant each); double-buffered LDS
//    (128 KiB); 8 x 8KB global_load_lds per K-tile issued 2/phase, ONE tile
//    ahead, order B0 B1 B2 B3 A0 A2 A1 A3
//  - counted vmcnt only: vmcnt(4) end of phase 1 (guards A1,A3 of current),
//    vmcnt(2) end of phase 3 (guards B0-3,A0,A2 of next) -- never 0 in loop
//  - chunk-XOR LDS swizzle (row&7) on both sides: pre-swizzled global source
//    for the linear DMA dest, XOR'd ds_read address (conflict-free, as before)
__global__ __launch_bounds__(512, 2) void gemm_i8_kernel(
    const signed char* __restrict__ A,   // [T][K] int8
    const signed char* __restrict__ B,   // [N][K] int8
    const float* __restrict__ bias,
    const float* __restrict__ scale_slot,
    const float* __restrict__ wscale,
    float* __restrict__ out, int K, int N) {
  __shared__ signed char As[2][256 * 128];
  __shared__ signed char Bs[2][256 * 128];

  const int tid = threadIdx.x;
  const int lane = tid & 63;
  const int wid = tid >> 6;

  // XCD-aware swizzle of flat block id (nwg = 256, divisible by 8)
  const int nwgx = gridDim.x;
  const int nwg = nwgx * gridDim.y;
  const int flat = blockIdx.y * nwgx + blockIdx.x;
  const int cpx = nwg >> 3;
  const int swz = (flat & 7) * cpx + (flat >> 3);
  const int row0 = (swz / nwgx) << 8;
  const int col0 = (swz % nwgx) << 8;

  const int wm = (wid >> 2) * 128;  // wave row block
  const int wn = (wid & 3) * 64;    // wave col block

  int4v acc[8][4] = {};

  // --- staging: one call = 512 thr x 16B = 8KB = 64 rows of 128B.
  // per call, wave wid covers rows wid*8..wid*8+8; LDS chunk c of row r
  // holds global chunk c ^ (r&7) -> lane loads global chunk (l&7)^((l>>3)&7)
  const int srow = wid * 8 + (lane >> 3);
  const int schunk = ((lane & 7) ^ ((lane >> 3) & 7)) << 4;
  const signed char* gA = A + (long)(row0 + srow) * K + schunk;
  const signed char* gB = B + (long)(col0 + srow) * K + schunk;
  const int sdst = wid * 1024;  // wave's 1KB within each 8KB call block

  // --- fragment reads: row r = base + (lane&15); desired chunk d = s*4+q;
  // LDS chunk = d ^ (r&7) = d ^ (lane&7)
  const int q = lane >> 4;
  const int c7 = lane & 7;
  const int fc0 = (q ^ c7) << 4;        // k-step 0
  const int fc1 = ((4 + q) ^ c7) << 4;  // k-step 1
  const int fa = (wm + (lane & 15)) * 128;
  const int fb = (wn + (lane & 15)) * 128;

  const long l64K = 64 * (long)K;
  const int NT = K >> 7;  // K-tiles of 128

  // ---- prologue: stage tile 0 into buf 0 (order B0 B1 B2 B3 A0 A2 A1 A3)
  async_ld16(gB, &Bs[0][0 * 8192 + sdst]);
  async_ld16(gB + l64K, &Bs[0][1 * 8192 + sdst]);
  async_ld16(gB + 2 * l64K, &Bs[0][2 * 8192 + sdst]);
  async_ld16(gB + 3 * l64K, &Bs[0][3 * 8192 + sdst]);
  async_ld16(gA, &As[0][0 * 8192 + sdst]);
  async_ld16(gA + 2 * l64K, &As[0][2 * 8192 + sdst]);
  async_ld16(gA + l64K, &As[0][1 * 8192 + sdst]);
  async_ld16(gA + 3 * l64K, &As[0][3 * 8192 + sdst]);
  asm volatile("s_waitcnt vmcnt(2)" ::: "memory");
  __builtin_amdgcn_s_barrier();

  int4v areg[4][2], breg0[2][2], breg1[2][2];

  for (int T = 0; T < NT; ++T) {
    const int b = T & 1;
    const int Tn = (T + 1 < NT) ? (T + 1) : T;  // last iter: harmless restage
    const signed char* gAn = gA + (long)Tn * 128;
    const signed char* gBn = gB + (long)Tn * 128;
    signed char* An = &As[b ^ 1][sdst];
    signed char* Bn = &Bs[b ^ 1][sdst];
    const signed char* Ab = As[b];
    const signed char* Bb = Bs[b];

    // ---- phase 0: quadrant (ih0, jh0); stage B0,B1 of next tile ----
#pragma unroll
    for (int i = 0; i < 4; i++) {
      areg[i][0] = *(const int4v*)(Ab + fa + i * 2048 + fc0);
      areg[i][1] = *(const int4v*)(Ab + fa + i * 2048 + fc1);
    }
#pragma unroll
    for (int j = 0; j < 2; j++) {
      breg0[j][0] = *(const int4v*)(Bb + fb + j * 2048 + fc0);
      breg0[j][1] = *(const int4v*)(Bb + fb + j * 2048 + fc1);
    }
    async_ld16(gBn, Bn);
    async_ld16(gBn + l64K, Bn + 8192);
    __builtin_amdgcn_s_barrier();
    asm volatile("s_waitcnt lgkmcnt(0)" ::: "memory");
    __builtin_amdgcn_s_setprio(1);
#pragma unroll
    for (int i = 0; i < 4; i++)
#pragma unroll
      for (int j = 0; j < 2; j++) {
        acc[i][j] = __builtin_amdgcn_mfma_i32_16x16x64_i8(areg[i][0], breg0[j][0], acc[i][j], 0, 0, 0);
        acc[i][j] = __builtin_amdgcn_mfma_i32_16x16x64_i8(areg[i][1], breg0[j][1], acc[i][j], 0, 0, 0);
      }
    __builtin_amdgcn_s_setprio(0);
    __builtin_amdgcn_s_barrier();

    // ---- phase 1: quadrant (ih0, jh1); stage B2,B3 of next tile ----
#pragma unroll
    for (int j = 0; j < 2; j++) {
      breg1[j][0] = *(const int4v*)(Bb + fb + (2 + j) * 2048 + fc0);
      breg1[j][1] = *(const int4v*)(Bb + fb + (2 + j) * 2048 + fc1);
    }
    async_ld16(gBn + 2 * l64K, Bn + 2 * 8192);
    async_ld16(gBn + 3 * l64K, Bn + 3 * 8192);
    __builtin_amdgcn_s_barrier();
    asm volatile("s_waitcnt lgkmcnt(0)" ::: "memory");
    __builtin_amdgcn_s_setprio(1);
#pragma unroll
    for (int i = 0; i < 4; i++)
#pragma unroll
      for (int j = 0; j < 2; j++) {
        acc[i][2 + j] = __builtin_amdgcn_mfma_i32_16x16x64_i8(areg[i][0], breg1[j][0], acc[i][2 + j], 0, 0, 0);
        acc[i][2 + j] = __builtin_amdgcn_mfma_i32_16x16x64_i8(areg[i][1], breg1[j][1], acc[i][2 + j], 0, 0, 0);
      }
    __builtin_amdgcn_s_setprio(0);
    // all 8 calls of CURRENT tile landed; 4 newer (B0-3 next) stay in flight
    asm volatile("s_waitcnt vmcnt(4)" ::: "memory");
    __builtin_amdgcn_s_barrier();

    // ---- phase 2: quadrant (ih1, jh0); stage A0,A2 of next tile ----
#pragma unroll
    for (int i = 0; i < 4; i++) {
      areg[i][0] = *(const int4v*)(Ab + fa + 8192 + i * 2048 + fc0);
      areg[i][1] = *(const int4v*)(Ab + fa + 8192 + i * 2048 + fc1);
    }
    async_ld16(gAn, An);
    async_ld16(gAn + 2 * l64K, An + 2 * 8192);
    __builtin_amdgcn_s_barrier();
    asm volatile("s_waitcnt lgkmcnt(0)" ::: "memory");
    __builtin_amdgcn_s_setprio(1);
#pragma unroll
    for (int i = 0; i < 4; i++)
#pragma unroll
      for (int j = 0; j < 2; j++) {
        acc[4 + i][j] = __builtin_amdgcn_mfma_i32_16x16x64_i8(areg[i][0], breg0[j][0], acc[4 + i][j], 0, 0, 0);
        acc[4 + i][j] = __builtin_amdgcn_mfma_i32_16x16x64_i8(areg[i][1], breg0[j][1], acc[4 + i][j], 0, 0, 0);
      }
    __builtin_amdgcn_s_setprio(0);
    __builtin_amdgcn_s_barrier();

    // ---- phase 3: quadrant (ih1, jh1); stage A1,A3 of next tile ----
    async_ld16(gAn + l64K, An + 8192);
    async_ld16(gAn + 3 * l64K, An + 3 * 8192);
    __builtin_amdgcn_s_barrier();
    __builtin_amdgcn_s_setprio(1);
#pragma unroll
    for (int i = 0; i < 4; i++)
#pragma unroll
      for (int j = 0; j < 2; j++) {
        acc[4 + i][2 + j] = __builtin_amdgcn_mfma_i32_16x16x64_i8(areg[i][0], breg1[j][0], acc[4 + i][2 + j], 0, 0, 0);
        acc[4 + i][2 + j] = __builtin_amdgcn_mfma_i32_16x16x64_i8(areg[i][1], breg1[j][1], acc[4 + i][2 + j], 0, 0, 0);
      }
    __builtin_amdgcn_s_setprio(0);
    // first 6 calls of NEXT tile (B0-3,A0,A2) landed; A1,A3 stay in flight
    asm volatile("s_waitcnt vmcnt(2)" ::: "memory");
    __builtin_amdgcn_s_barrier();
  }

  asm volatile("s_waitcnt vmcnt(0)" ::: "memory");  // drain tail restage

  // epilogue: dequant + bias. C/D: col = lane&15, row = (lane>>4)*4 + reg
  const float s = scale_slot[0] * wscale[0];
  const int orow = row0 + wm + (q << 2);
  const int ocol = col0 + wn + (lane & 15);
#pragma unroll
  for (int jj = 0; jj < 4; jj++) {
    const int c = ocol + jj * 16;
    const float bv = bias[c];
#pragma unroll
    for (int i = 0; i < 8; i++) {
#pragma unroll
      for (int r = 0; r < 4; r++) {
        out[(long)(orow + i * 16 + r) * N + c] = (float)acc[i][jj][r] * s + bv;
      }
    }
  }
}

extern "C" void kernel_launch(void* const* d_in, const int* in_sizes, int n_in,
                              void* d_out, int out_size, void* d_ws,
                              size_t ws_size, hipStream_t stream) {
  const float* x = (const float*)d_in[0];
  const int* w = (const int*)d_in[1];
  const float* wscale = (const float*)d_in[2];
  const float* bias = (const float*)d_in[3];
  float* out = (float*)d_out;

  const int OUT_F = in_sizes[3];
  const int IN_F = in_sizes[1] / OUT_F;
  const int TOKENS = in_sizes[0] / IN_F;

  float* partial = (float*)d_ws;                       // 1024 floats
  float* scale_slot = partial + NB_MAX;                // 1 float
  signed char* qx = (signed char*)d_ws + 8192;
  signed char* qw = qx + (size_t)TOKENS * IN_F;

  const int nx4 = TOKENS * IN_F / 4;
  const int nw4 = OUT_F * IN_F / 4;

  absmax_partial_kernel<<<NB_MAX, 256, 0, stream>>>(x, partial, nx4);

  const int nmax = nx4 > nw4 ? nx4 : nw4;
  quant_pack_kernel<<<(nmax + 255) / 256, 256, 0, stream>>>(
      x, w, partial, scale_slot, (int*)qx, (int*)qw, nx4, nw4);

  dim3 grid(OUT_F / 256, TOKENS / 256);
  gemm_i8_kernel<<<grid, 512, 0, stream>>>(qx, qw, bias, scale_slot, wscale,
                                           out, IN_F, OUT_F);
}

// Round 3
// 244.647 us; speedup vs baseline: 1.0610x; 1.0048x over previous
//
#include <hip/hip_runtime.h>

typedef __attribute__((ext_vector_type(4))) int int4v;

#define NB_MAX 1024  // partial-max array length

// --- async global->LDS, 16B per lane, wave-uniform LDS base ---
__device__ __forceinline__ void async_ld16(const void* g, void* l) {
  __builtin_amdgcn_global_load_lds(
      (const __attribute__((address_space(1))) void*)g,
      (__attribute__((address_space(3))) void*)l,
      16, 0, 0);
}

// ---- 1) absmax partials over x  +  fused w -> int8 pack (independent) ----
__global__ void absmax_wpack_kernel(const float* __restrict__ x,
                                    const int* __restrict__ w,
                                    float* __restrict__ partial,
                                    int* __restrict__ qw, int n4, int nw4) {
  const float4* x4 = (const float4*)x;
  float m = 0.0f;
  const int stride = gridDim.x * blockDim.x;
  const int i0 = blockIdx.x * blockDim.x + threadIdx.x;
  for (int i = i0; i < n4; i += stride) {
    float4 v = x4[i];
    m = fmaxf(m, fabsf(v.x));
    m = fmaxf(m, fabsf(v.y));
    m = fmaxf(m, fabsf(v.z));
    m = fmaxf(m, fabsf(v.w));
  }
  // w-pack: int32x4 -> 4x int8 packed into one int (independent of absmax)
  for (int i = i0; i < nw4; i += stride) {
    int4 v = ((const int4*)w)[i];
    unsigned int p = (unsigned int)(v.x & 255) |
                     ((unsigned int)(v.y & 255) << 8) |
                     ((unsigned int)(v.z & 255) << 16) |
                     ((unsigned int)(v.w & 255) << 24);
    qw[i] = (int)p;
  }
#pragma unroll
  for (int off = 32; off > 0; off >>= 1)
    m = fmaxf(m, __shfl_down(m, off, 64));
  __shared__ float wmax[4];
  const int wid = threadIdx.x >> 6;
  if ((threadIdx.x & 63) == 0) wmax[wid] = m;
  __syncthreads();
  if (threadIdx.x == 0)
    partial[blockIdx.x] =
        fmaxf(fmaxf(wmax[0], wmax[1]), fmaxf(wmax[2], wmax[3]));
}

// block-wide reduce of the 1024 partials (every block recomputes; ~L2 hits)
__device__ __forceinline__ float reduce_partials(const float* partial) {
  __shared__ float smax;
  float m = 0.0f;
  for (int i = threadIdx.x; i < NB_MAX; i += blockDim.x)
    m = fmaxf(m, partial[i]);
#pragma unroll
  for (int off = 32; off > 0; off >>= 1)
    m = fmaxf(m, __shfl_down(m, off, 64));
  __shared__ float wmax[4];
  const int wid = threadIdx.x >> 6;
  if ((threadIdx.x & 63) == 0) wmax[wid] = m;
  __syncthreads();
  if (threadIdx.x == 0)
    smax = fmaxf(fmaxf(wmax[0], wmax[1]), fmaxf(wmax[2], wmax[3]));
  __syncthreads();
  return smax;
}

// ---------------- 2) quantize x -> int8 (grid-stride) ----------------------
__global__ void quant_x_kernel(const float* __restrict__ x,
                               const float* __restrict__ partial,
                               float* __restrict__ scale_slot,
                               int* __restrict__ qx, int nx4) {
  const float scale = reduce_partials(partial) / 127.0f;
  if (blockIdx.x == 0 && threadIdx.x == 0) *scale_slot = scale;
  const int stride = gridDim.x * blockDim.x;
  for (int i = blockIdx.x * blockDim.x + threadIdx.x; i < nx4; i += stride) {
    float4 v = ((const float4*)x)[i];
    // IEEE division + rint (half-to-even) matches jnp.round(t/scale)
    int q0 = (int)fminf(fmaxf(rintf(v.x / scale), -127.0f), 127.0f);
    int q1 = (int)fminf(fmaxf(rintf(v.y / scale), -127.0f), 127.0f);
    int q2 = (int)fminf(fmaxf(rintf(v.z / scale), -127.0f), 127.0f);
    int q3 = (int)fminf(fmaxf(rintf(v.w / scale), -127.0f), 127.0f);
    unsigned int p = (unsigned int)(q0 & 255) |
                     ((unsigned int)(q1 & 255) << 8) |
                     ((unsigned int)(q2 & 255) << 16) |
                     ((unsigned int)(q3 & 255) << 24);
    qx[i] = (int)p;
  }
}

// ---------------- 3) int8 GEMM: 256x256 tile, 8-wave, 4-phase pipeline ----
// Schedule (R2, gaps all >= 2 phases, strictly more relaxed than proven R1):
//   ph0 stages all B of next tile, ph1 stages all A (A1,A3 issued last).
//   Invariant entering iter T: outstanding = {A1,A3 of T}.
//   ph1-end: 2 old + 8 new -> vmcnt(8) drains A1,A3 of T (issue gap 4 ph)
//   ph3-end: 8 new -> vmcnt(2) drains B0-3,A0,A2 of T+1 (gap 2-3 ph)
//   Last iter stages nothing; ph1-end wait becomes vmcnt(0) (trivial).
// Epilogue: per-wave LDS round-trip -> float4 stores; cross-lane LDS
// write->read REQUIRES the lgkmcnt(0) fence (R2's missing fence = NaN bug).
__global__ __launch_bounds__(512, 2) void gemm_i8_kernel(
    const signed char* __restrict__ A,   // [T][K] int8
    const signed char* __restrict__ B,   // [N][K] int8
    const float* __restrict__ bias,
    const float* __restrict__ scale_slot,
    const float* __restrict__ wscale,
    float* __restrict__ out, int K, int N) {
  __shared__ signed char As[2][256 * 128];
  __shared__ signed char Bs[2][256 * 128];

  const int tid = threadIdx.x;
  const int lane = tid & 63;
  const int wid = tid >> 6;

  // XCD-aware swizzle of flat block id (nwg = 256, divisible by 8)
  const int nwgx = gridDim.x;
  const int nwg = nwgx * gridDim.y;
  const int flat = blockIdx.y * nwgx + blockIdx.x;
  const int cpx = nwg >> 3;
  const int swz = (flat & 7) * cpx + (flat >> 3);
  const int row0 = (swz / nwgx) << 8;
  const int col0 = (swz % nwgx) << 8;

  const int wm = (wid >> 2) * 128;  // wave row block
  const int wn = (wid & 3) * 64;    // wave col block

  int4v acc[8][4] = {};

  // --- staging: one call = 512 thr x 16B = 8KB = 64 rows of 128B.
  // per call, wave wid covers 8 rows; LDS chunk c of row r holds global
  // chunk c ^ (r&7) -> lane loads global chunk (l&7)^((l>>3)&7)
  const int srow = wid * 8 + (lane >> 3);
  const int schunk = ((lane & 7) ^ ((lane >> 3) & 7)) << 4;
  const signed char* gA = A + (long)(row0 + srow) * K + schunk;
  const signed char* gB = B + (long)(col0 + srow) * K + schunk;
  const int sdst = wid * 1024;  // wave's 1KB within each 8KB call block

  // --- fragment reads: row r = base + (lane&15); desired chunk d = s*4+q;
  // LDS chunk = d ^ (r&7) = d ^ (lane&7)
  const int q = lane >> 4;
  const int c7 = lane & 7;
  const int fc0 = (q ^ c7) << 4;        // k-step 0
  const int fc1 = ((4 + q) ^ c7) << 4;  // k-step 1
  const int fa = (wm + (lane & 15)) * 128;
  const int fb = (wn + (lane & 15)) * 128;

  const long l64K = 64 * (long)K;
  const int NT = K >> 7;  // K-tiles of 128

  // ---- prologue: stage tile 0 into buf 0 (order B0-3, A0, A2, A1, A3)
  async_ld16(gB, &Bs[0][0 * 8192 + sdst]);
  async_ld16(gB + l64K, &Bs[0][1 * 8192 + sdst]);
  async_ld16(gB + 2 * l64K, &Bs[0][2 * 8192 + sdst]);
  async_ld16(gB + 3 * l64K, &Bs[0][3 * 8192 + sdst]);
  async_ld16(gA, &As[0][0 * 8192 + sdst]);
  async_ld16(gA + 2 * l64K, &As[0][2 * 8192 + sdst]);
  async_ld16(gA + l64K, &As[0][1 * 8192 + sdst]);
  async_ld16(gA + 3 * l64K, &As[0][3 * 8192 + sdst]);
  asm volatile("s_waitcnt vmcnt(2)" ::: "memory");
  __builtin_amdgcn_s_barrier();

  int4v areg[4][2], breg0[2][2], breg1[2][2];

  for (int T = 0; T < NT; ++T) {
    const int b = T & 1;
    const bool pf = (T + 1 < NT);
    const signed char* gAn = gA + (long)(T + 1) * 128;
    const signed char* gBn = gB + (long)(T + 1) * 128;
    signed char* An = &As[b ^ 1][sdst];
    signed char* Bn = &Bs[b ^ 1][sdst];
    const signed char* Ab = As[b];
    const signed char* Bb = Bs[b];

    // ---- phase 0: quadrant (loA, jh0); stage ALL B of next tile ----
#pragma unroll
    for (int i = 0; i < 4; i++) {
      areg[i][0] = *(const int4v*)(Ab + fa + i * 2048 + fc0);
      areg[i][1] = *(const int4v*)(Ab + fa + i * 2048 + fc1);
    }
#pragma unroll
    for (int j = 0; j < 2; j++) {
      breg0[j][0] = *(const int4v*)(Bb + fb + j * 2048 + fc0);
      breg0[j][1] = *(const int4v*)(Bb + fb + j * 2048 + fc1);
    }
    if (pf) {
      async_ld16(gBn, Bn);
      async_ld16(gBn + l64K, Bn + 8192);
      async_ld16(gBn + 2 * l64K, Bn + 2 * 8192);
      async_ld16(gBn + 3 * l64K, Bn + 3 * 8192);
    }
    __builtin_amdgcn_s_barrier();
    asm volatile("s_waitcnt lgkmcnt(0)" ::: "memory");
    __builtin_amdgcn_s_setprio(1);
#pragma unroll
    for (int i = 0; i < 4; i++)
#pragma unroll
      for (int j = 0; j < 2; j++) {
        acc[i][j] = __builtin_amdgcn_mfma_i32_16x16x64_i8(areg[i][0], breg0[j][0], acc[i][j], 0, 0, 0);
        acc[i][j] = __builtin_amdgcn_mfma_i32_16x16x64_i8(areg[i][1], breg0[j][1], acc[i][j], 0, 0, 0);
      }
    __builtin_amdgcn_s_setprio(0);
    __builtin_amdgcn_s_barrier();

    // ---- phase 1: quadrant (loA, jh1); stage ALL A of next tile ----
#pragma unroll
    for (int j = 0; j < 2; j++) {
      breg1[j][0] = *(const int4v*)(Bb + fb + (2 + j) * 2048 + fc0);
      breg1[j][1] = *(const int4v*)(Bb + fb + (2 + j) * 2048 + fc1);
    }
    if (pf) {
      async_ld16(gAn, An);
      async_ld16(gAn + 2 * l64K, An + 2 * 8192);
      async_ld16(gAn + l64K, An + 8192);          // A1 issued 2nd-to-last
      async_ld16(gAn + 3 * l64K, An + 3 * 8192);  // A3 issued last
    }
    __builtin_amdgcn_s_barrier();
    asm volatile("s_waitcnt lgkmcnt(0)" ::: "memory");
    __builtin_amdgcn_s_setprio(1);
#pragma unroll
    for (int i = 0; i < 4; i++)
#pragma unroll
      for (int j = 0; j < 2; j++) {
        acc[i][2 + j] = __builtin_amdgcn_mfma_i32_16x16x64_i8(areg[i][0], breg1[j][0], acc[i][2 + j], 0, 0, 0);
        acc[i][2 + j] = __builtin_amdgcn_mfma_i32_16x16x64_i8(areg[i][1], breg1[j][1], acc[i][2 + j], 0, 0, 0);
      }
    __builtin_amdgcn_s_setprio(0);
    // need A1,A3 of CURRENT tile landed before ph2 reads them.
    if (pf) {
      asm volatile("s_waitcnt vmcnt(8)" ::: "memory");
    } else {
      asm volatile("s_waitcnt vmcnt(0)" ::: "memory");
    }
    __builtin_amdgcn_s_barrier();

    // ---- phase 2: quadrant (hiA, jh0) ----
#pragma unroll
    for (int i = 0; i < 4; i++) {
      areg[i][0] = *(const int4v*)(Ab + fa + 8192 + i * 2048 + fc0);
      areg[i][1] = *(const int4v*)(Ab + fa + 8192 + i * 2048 + fc1);
    }
    __builtin_amdgcn_s_barrier();
    asm volatile("s_waitcnt lgkmcnt(0)" ::: "memory");
    __builtin_amdgcn_s_setprio(1);
#pragma unroll
    for (int i = 0; i < 4; i++)
#pragma unroll
      for (int j = 0; j < 2; j++) {
        acc[4 + i][j] = __builtin_amdgcn_mfma_i32_16x16x64_i8(areg[i][0], breg0[j][0], acc[4 + i][j], 0, 0, 0);
        acc[4 + i][j] = __builtin_amdgcn_mfma_i32_16x16x64_i8(areg[i][1], breg0[j][1], acc[4 + i][j], 0, 0, 0);
      }
    __builtin_amdgcn_s_setprio(0);
    __builtin_amdgcn_s_barrier();

    // ---- phase 3: quadrant (hiA, jh1) ----
    __builtin_amdgcn_s_barrier();
    __builtin_amdgcn_s_setprio(1);
#pragma unroll
    for (int i = 0; i < 4; i++)
#pragma unroll
      for (int j = 0; j < 2; j++) {
        acc[4 + i][2 + j] = __builtin_amdgcn_mfma_i32_16x16x64_i8(areg[i][0], breg1[j][0], acc[4 + i][2 + j], 0, 0, 0);
        acc[4 + i][2 + j] = __builtin_amdgcn_mfma_i32_16x16x64_i8(areg[i][1], breg1[j][1], acc[4 + i][2 + j], 0, 0, 0);
      }
    __builtin_amdgcn_s_setprio(0);
    // B0-3, A0, A2 of NEXT tile landed; A1, A3 stay in flight
    asm volatile("s_waitcnt vmcnt(2)" ::: "memory");
    __builtin_amdgcn_s_barrier();
  }

  // drain + sync before reusing LDS for the store-coalescing round-trip
  asm volatile("s_waitcnt vmcnt(0)" ::: "memory");
  __syncthreads();

  // epilogue: dequant + bias, staged through LDS for coalesced stores.
  // acc[g][jj][r] holds out[row0+wm+g*16+q*4+r][col0+wn+(lane&15)+16*jj].
  // Per wave: 2 alternating 4KB regions (16 rows x 64 f32), private to wave.
  // Cross-lane LDS write->read within the wave: MUST fence with lgkmcnt(0)
  // before readback (the missing fence was R2's NaN bug).
  float* lds = (float*)&As[0][0];  // 8 waves x 2 x 1024 f32 = 64 KB
  const float s = scale_slot[0] * wscale[0];
  const int l15 = lane & 15;
  float bv[4];
#pragma unroll
  for (int jj = 0; jj < 4; jj++) bv[jj] = bias[col0 + wn + l15 + jj * 16];
  const int wbase = wid << 11;  // wid * 2048 floats
#pragma unroll
  for (int g = 0; g < 8; ++g) {
    float* reg = lds + wbase + ((g & 1) << 10);
#pragma unroll
    for (int jj = 0; jj < 4; jj++)
#pragma unroll
      for (int r = 0; r < 4; r++)
        reg[(q * 4 + r) * 64 + l15 + jj * 16] = (float)acc[g][jj][r] * s + bv[jj];
    // fence: all LDS writes of this group committed before cross-lane reads
    asm volatile("s_waitcnt lgkmcnt(0)" ::: "memory");
    __builtin_amdgcn_sched_barrier(0);
    // readback: 16 lanes per row -> 256B-contiguous global rows
#pragma unroll
    for (int rr = 0; rr < 4; rr++) {
      const int row = q + rr * 4;
      float4 v = *(const float4*)(reg + row * 64 + l15 * 4);
      *(float4*)(out + (long)(row0 + wm + g * 16 + row) * N + col0 + wn +
                 l15 * 4) = v;
    }
  }
}

extern "C" void kernel_launch(void* const* d_in, const int* in_sizes, int n_in,
                              void* d_out, int out_size, void* d_ws,
                              size_t ws_size, hipStream_t stream) {
  const float* x = (const float*)d_in[0];
  const int* w = (const int*)d_in[1];
  const float* wscale = (const float*)d_in[2];
  const float* bias = (const float*)d_in[3];
  float* out = (float*)d_out;

  const int OUT_F = in_sizes[3];
  const int IN_F = in_sizes[1] / OUT_F;
  const int TOKENS = in_sizes[0] / IN_F;

  float* partial = (float*)d_ws;                       // 1024 floats
  float* scale_slot = partial + NB_MAX;                // 1 float
  signed char* qx = (signed char*)d_ws + 8192;
  signed char* qw = qx + (size_t)TOKENS * IN_F;

  const int nx4 = TOKENS * IN_F / 4;
  const int nw4 = OUT_F * IN_F / 4;

  absmax_wpack_kernel<<<NB_MAX, 256, 0, stream>>>(x, w, partial, (int*)qw,
                                                  nx4, nw4);

  quant_x_kernel<<<2048, 256, 0, stream>>>(x, partial, scale_slot, (int*)qx,
                                           nx4);

  dim3 grid(OUT_F / 256, TOKENS / 256);
  gemm_i8_kernel<<<grid, 512, 0, stream>>>(qx, qw, bias, scale_slot, wscale,
                                           out, IN_F, OUT_F);
}